// Round 1
// baseline (426.450 us; speedup 1.0000x reference)
//
#include <hip/hip_runtime.h>
#include <hip/hip_bf16.h>

// ARNOLD_ENC: spike-latency encoding.
//   times[b, f*8+c] = 2.5 * |trace[b,f] - center[c]|   (f32, IEEE)
//   spike at t = int(times/0.1 + 1) iff times <= 10.0 and bin < 100
//   out: int32[100][1024][1024], each (b,n) has at most one 1.
// Pure store-BW problem: 400 MB output, ~64 us floor at 6.3 TB/s.
// One fused pass: every output element written exactly once (no memset).

#define BB 1024   // batch
#define FF 128    // features
#define CC 8      // centers
#define NN 1024   // FF*CC
#define TT 100    // time steps
#define TCHUNK 25 // t steps per block (grid.y = 4)

__global__ __launch_bounds__(256) void ARNOLD_ENC_52639119180424_kernel(
        const float* __restrict__ trace,
        const float* __restrict__ center,
        int* __restrict__ out) {
    const int b   = blockIdx.x;          // 0..1023
    const int tc  = blockIdx.y;          // 0..3
    const int tid = threadIdx.x;         // 0..255
    const int n0  = tid << 2;            // 4 consecutive n, same f (n0 % 8 in {0,4})
    const int f   = n0 >> 3;
    const int c0  = n0 & 7;              // 0 or 4

    const float x = trace[b * FF + f];

    int bins[4];
#pragma unroll
    for (int i = 0; i < 4; ++i) {
        // IEEE f32 ops, division correctly rounded (no fast-math) -> matches np/jnp bit-exactly.
        float tms = 2.5f * fabsf(x - center[c0 + i]);
        int bin = -1;                    // -1 = no spike
        if (!(tms > 10.0f)) {
            int bb = (int)(tms / 0.1f + 1.0f);   // trunc == floor (tms >= 0)
            if (bb < TT) bin = bb;               // bb >= 1 always
        }
        bins[i] = bin;
    }

    int* outp = out + (size_t)b * NN + n0;
    const int tbase = tc * TCHUNK;
#pragma unroll
    for (int t = 0; t < TCHUNK; ++t) {
        const int ttime = tbase + t;
        int4 v;
        v.x = (bins[0] == ttime) ? 1 : 0;
        v.y = (bins[1] == ttime) ? 1 : 0;
        v.z = (bins[2] == ttime) ? 1 : 0;
        v.w = (bins[3] == ttime) ? 1 : 0;
        *(int4*)(outp + (size_t)ttime * ((size_t)BB * NN)) = v;  // coalesced 16B/lane
    }
}

extern "C" void kernel_launch(void* const* d_in, const int* in_sizes, int n_in,
                              void* d_out, int out_size, void* d_ws, size_t ws_size,
                              hipStream_t stream) {
    const float* trace  = (const float*)d_in[0];   // [1024,128] f32
    const float* center = (const float*)d_in[1];   // [8] f32
    int* out = (int*)d_out;                        // [100][1024][1024] int32

    dim3 grid(BB, TT / TCHUNK);   // (1024, 4)
    ARNOLD_ENC_52639119180424_kernel<<<grid, 256, 0, stream>>>(trace, center, out);
}

// Round 2
// 423.287 us; speedup vs baseline: 1.0075x; 1.0075x over previous
//
#include <hip/hip_runtime.h>
#include <hip/hip_bf16.h>

// ARNOLD_ENC: spike-latency encoding.
//   bin(b,n) = int(2.5*|trace[b,f]-center[c]| / 0.1 + 1), spike at t=bin iff times<=10 and bin<100.
//   out: int32[100][1024][1024] = 400 MiB. Pure store-BW problem (~65 us floor at 6.3 TB/s).
//
// R1 finding: per-block t-strided writes (4 KB bursts at 4 MiB stride) reached only ~2.6 TB/s;
// the harness's own fill hits 6.3 TB/s with contiguous streams. So: two phases.
//   Phase 1: bins -> d_ws as uint8[1024*1024] (1..101; >=100 never equals t<=99 -> free masking).
//   Phase 2: contiguous grid-stride stream: each block writes one 100 KB contiguous chunk,
//            t = g>>18 (groups/plane = 2^18), bins via uchar4 L2-hit loads.

#define BB 1024
#define FF 128
#define NN 1024
#define TT 100
#define GROUPS_PER_PLANE ((BB * NN) / 4)        // 262144 = 1 << 18
#define NGROUPS (TT * GROUPS_PER_PLANE)          // 26,214,400 int4 groups
#define P2_BLOCKS 4096
#define P2_THREADS 256
#define P2_ITERS (NGROUPS / (P2_BLOCKS * P2_THREADS))   // 25

__global__ __launch_bounds__(256) void arnold_bins_kernel(
        const float* __restrict__ trace,
        const float* __restrict__ center,
        uchar4* __restrict__ bins) {
    const int b   = blockIdx.x;      // 0..1023
    const int tid = threadIdx.x;     // 0..255
    const int n0  = tid << 2;        // 4 consecutive n, same f
    const int f   = n0 >> 3;
    const int c0  = n0 & 7;

    const float x = trace[b * FF + f];

    unsigned char v[4];
#pragma unroll
    for (int i = 0; i < 4; ++i) {
        // IEEE f32 (no fast-math): matches np/jnp binning bit-exactly.
        float tms = 2.5f * fabsf(x - center[c0 + i]);
        unsigned bb = (tms > 10.0f) ? 255u : (unsigned)(tms / 0.1f + 1.0f);  // 1..101 or 255
        v[i] = (unsigned char)bb;    // values >= 100 never match t in [0,99]
    }
    bins[(b << 8) + tid] = make_uchar4(v[0], v[1], v[2], v[3]);
}

__global__ __launch_bounds__(256) void arnold_stream_kernel(
        const uchar4* __restrict__ bins,
        int4* __restrict__ out) {
    // Block j owns int4-groups [j*6400, (j+1)*6400): one contiguous 100 KB stream.
    const int base = blockIdx.x * (P2_ITERS * P2_THREADS) + threadIdx.x;
#pragma unroll
    for (int k = 0; k < P2_ITERS; ++k) {
        const int g = base + k * P2_THREADS;
        const int t = g >> 18;                      // plane index (0..99)
        const int p = g & (GROUPS_PER_PLANE - 1);   // group within plane
        const uchar4 c = bins[p];                   // 4B/lane, coalesced, L2-resident (1 MB)
        int4 v;
        v.x = (c.x == t) ? 1 : 0;
        v.y = (c.y == t) ? 1 : 0;
        v.z = (c.z == t) ? 1 : 0;
        v.w = (c.w == t) ? 1 : 0;
        out[g] = v;                                 // 16B/lane, fully sequential per block
    }
}

extern "C" void kernel_launch(void* const* d_in, const int* in_sizes, int n_in,
                              void* d_out, int out_size, void* d_ws, size_t ws_size,
                              hipStream_t stream) {
    const float* trace  = (const float*)d_in[0];   // [1024,128] f32
    const float* center = (const float*)d_in[1];   // [8] f32
    uchar4* bins = (uchar4*)d_ws;                  // 1 MiB scratch, fully rewritten each call
    int4* out = (int4*)d_out;                      // [100][1024][1024] int32

    arnold_bins_kernel<<<BB, 256, 0, stream>>>(trace, center, bins);
    arnold_stream_kernel<<<P2_BLOCKS, P2_THREADS, 0, stream>>>(bins, out);
}

// Round 4
// 419.943 us; speedup vs baseline: 1.0155x; 1.0080x over previous
//
#include <hip/hip_runtime.h>
#include <hip/hip_bf16.h>

// ARNOLD_ENC: spike-latency encoding.
//   bin(b,n) = int(2.5*|trace[b,f]-center[c]| / 0.1 + 1); spike at t=bin iff times<=10 and bin<100.
//   out: int32[100][1024][1024] = 400 MiB. Pure store-BW problem (~65 us floor at 6.3 TB/s).
//
// R1: t-strided 4KB-burst writes   -> kernel ~161 us (~2.5 TB/s).
// R2: fully contiguous block writes -> kernel ~158 us. NEUTRAL => not a DRAM-locality problem.
// R3/R4 theory: regular stores allocate+evict in L2 capping write BW ~2.5 TB/s; the 6.33 TB/s
//   harness fill uses streaming stores. Fix: __builtin_nontemporal_store (needs a NATIVE
//   clang vector type -- HIP's int4 class is rejected by the builtin).

#define BB 1024
#define FF 128
#define NN 1024
#define TT 100
#define GROUPS_PER_PLANE ((BB * NN) / 4)        // 262144 = 1 << 18
#define NGROUPS (TT * GROUPS_PER_PLANE)          // 26,214,400 int4 groups
#define P2_BLOCKS 4096
#define P2_THREADS 256
#define P2_ITERS (NGROUPS / (P2_BLOCKS * P2_THREADS))   // 25

typedef int iv4 __attribute__((ext_vector_type(4)));   // native vector: builtin-compatible

__global__ __launch_bounds__(256) void arnold_bins_kernel(
        const float* __restrict__ trace,
        const float* __restrict__ center,
        uchar4* __restrict__ bins) {
    const int b   = blockIdx.x;      // 0..1023
    const int tid = threadIdx.x;     // 0..255
    const int n0  = tid << 2;        // 4 consecutive n, same f
    const int f   = n0 >> 3;
    const int c0  = n0 & 7;

    const float x = trace[b * FF + f];

    unsigned char v[4];
#pragma unroll
    for (int i = 0; i < 4; ++i) {
        // IEEE f32 (no fast-math): matches np/jnp binning bit-exactly.
        float tms = 2.5f * fabsf(x - center[c0 + i]);
        unsigned bb = (tms > 10.0f) ? 255u : (unsigned)(tms / 0.1f + 1.0f);  // 1..101 or 255
        v[i] = (unsigned char)bb;    // values >= 100 never match t in [0,99]
    }
    bins[(b << 8) + tid] = make_uchar4(v[0], v[1], v[2], v[3]);
}

__global__ __launch_bounds__(256) void arnold_stream_kernel(
        const uchar4* __restrict__ bins,
        iv4* __restrict__ out) {
    // Block j owns int4-groups [j*6400, (j+1)*6400): one contiguous 100 KB stream.
    const int base = blockIdx.x * (P2_ITERS * P2_THREADS) + threadIdx.x;
#pragma unroll
    for (int k = 0; k < P2_ITERS; ++k) {
        const int g = base + k * P2_THREADS;
        const int t = g >> 18;                      // plane index (0..99)
        const int p = g & (GROUPS_PER_PLANE - 1);   // group within plane
        const uchar4 c = bins[p];                   // 4B/lane, coalesced, L2-resident (1 MB)
        iv4 v;
        v.x = (c.x == t) ? 1 : 0;
        v.y = (c.y == t) ? 1 : 0;
        v.z = (c.z == t) ? 1 : 0;
        v.w = (c.w == t) ? 1 : 0;
        __builtin_nontemporal_store(v, &out[g]);    // streaming store: no L2 allocate
    }
}

extern "C" void kernel_launch(void* const* d_in, const int* in_sizes, int n_in,
                              void* d_out, int out_size, void* d_ws, size_t ws_size,
                              hipStream_t stream) {
    const float* trace  = (const float*)d_in[0];   // [1024,128] f32
    const float* center = (const float*)d_in[1];   // [8] f32
    uchar4* bins = (uchar4*)d_ws;                  // 1 MiB scratch, fully rewritten each call
    iv4* out = (iv4*)d_out;                        // [100][1024][1024] int32

    arnold_bins_kernel<<<BB, 256, 0, stream>>>(trace, center, bins);
    arnold_stream_kernel<<<P2_BLOCKS, P2_THREADS, 0, stream>>>(bins, out);
}

// Round 5
// 416.485 us; speedup vs baseline: 1.0239x; 1.0083x over previous
//
#include <hip/hip_runtime.h>
#include <hip/hip_bf16.h>

// ARNOLD_ENC: spike-latency encoding.
//   bin(b,n) = int(2.5*|trace[b,f]-center[c]| / 0.1 + 1); spike at t=bin iff times<=10 and bin<100.
//   out: int32[100][1024][1024] = 400 MiB. Store-BW bound; 66 us floor at the fill's 6.33 TB/s.
//
// Measurement decomposition (R4): per timed iter = d_ws poison 1600 MiB (265 us, top-5) +
//   d_out poison 400 MiB (~66 us) + our kernels (~89 us). Controllable headroom ~17 us.
// R1: t-strided 4KB bursts, regular stores  -> ~95 us kernels
// R2: contiguous stream, regular stores     -> ~92 us (pattern: neutral)
// R4: contiguous stream, nontemporal stores -> ~89 us (NT: -3 us; L2-allocate theory wrong)
// R5 theory: per-store global bins load in the vmcnt queue throttles the store stream.
//   Stage each block's bins window in LDS ONCE, reuse across 10 t-planes -> pure-store loop.

#define BB 1024
#define FF 128
#define NN 1024
#define TT 100
#define GROUPS_PER_PLANE ((BB * NN) / 4)   // 262144 int4 groups per t-plane
#define WINDOW 2048                         // groups per window (8 KB bins in LDS)
#define WINS (GROUPS_PER_PLANE / WINDOW)    // 128 windows per plane
#define PCH 10                              // planes per block
#define PCHUNKS (TT / PCH)                  // 10

typedef int iv4 __attribute__((ext_vector_type(4)));   // native vector for nontemporal builtin

__global__ __launch_bounds__(256) void arnold_bins_kernel(
        const float* __restrict__ trace,
        const float* __restrict__ center,
        uchar4* __restrict__ bins) {
    const int b   = blockIdx.x;      // 0..1023
    const int tid = threadIdx.x;     // 0..255
    const int n0  = tid << 2;        // 4 consecutive n, same f
    const int f   = n0 >> 3;
    const int c0  = n0 & 7;

    const float x = trace[b * FF + f];

    unsigned char v[4];
#pragma unroll
    for (int i = 0; i < 4; ++i) {
        // IEEE f32 (no fast-math): matches np/jnp binning bit-exactly.
        float tms = 2.5f * fabsf(x - center[c0 + i]);
        unsigned bb = (tms > 10.0f) ? 255u : (unsigned)(tms / 0.1f + 1.0f);  // 1..101 or 255
        v[i] = (unsigned char)bb;    // values >= 100 never match t in [0,99]
    }
    bins[(b << 8) + tid] = make_uchar4(v[0], v[1], v[2], v[3]);
}

__global__ __launch_bounds__(256) void arnold_stream_kernel(
        const uchar4* __restrict__ bins,
        iv4* __restrict__ out) {
    __shared__ uchar4 lb[WINDOW];
    const int w   = blockIdx.x;      // 0..127  window within plane
    const int pc  = blockIdx.y;      // 0..9    plane chunk
    const int tid = threadIdx.x;

    // Stage this window's bins in LDS once (global loads OUT of the store loop).
    const uchar4* bw = bins + w * WINDOW;
#pragma unroll
    for (int i = 0; i < WINDOW / 256; ++i) lb[i * 256 + tid] = bw[i * 256 + tid];
    __syncthreads();

    const int t0 = pc * PCH;
    iv4* base = out + (size_t)w * WINDOW;
    for (int tt = 0; tt < PCH; ++tt) {
        const int t = t0 + tt;
        iv4* op = base + (size_t)t * GROUPS_PER_PLANE;   // 32 KB contiguous burst per plane
#pragma unroll
        for (int i = 0; i < WINDOW / 256; ++i) {         // 8 stores/thread/plane
            const int idx = i * 256 + tid;
            const uchar4 c = lb[idx];                    // stride-1 LDS: conflict-free
            iv4 v;
            v.x = (c.x == t) ? 1 : 0;
            v.y = (c.y == t) ? 1 : 0;
            v.z = (c.z == t) ? 1 : 0;
            v.w = (c.w == t) ? 1 : 0;
            __builtin_nontemporal_store(v, &op[idx]);    // pure store stream
        }
    }
}

extern "C" void kernel_launch(void* const* d_in, const int* in_sizes, int n_in,
                              void* d_out, int out_size, void* d_ws, size_t ws_size,
                              hipStream_t stream) {
    const float* trace  = (const float*)d_in[0];   // [1024,128] f32
    const float* center = (const float*)d_in[1];   // [8] f32
    uchar4* bins = (uchar4*)d_ws;                  // 1 MiB scratch, fully rewritten each call
    iv4* out = (iv4*)d_out;                        // [100][1024][1024] int32

    arnold_bins_kernel<<<BB, 256, 0, stream>>>(trace, center, bins);
    dim3 grid(WINS, PCHUNKS);                      // (128, 10) = 1280 blocks
    arnold_stream_kernel<<<grid, 256, 0, stream>>>(bins, out);
}